// Round 3
// baseline (373.053 us; speedup 1.0000x reference)
//
#include <hip/hip_runtime.h>
#include <hip/hip_bf16.h>

// W8Linear: out[32,16384] = (x[32,4096] . W[16384,4096]^T) * scale[n] + bias[n]
// Harness dtype reality: x/scale/bias fp32 buffers (fp16 promoted); weight
// int32 (268 MB); out FLOAT32. Correct since R3 (absmax 2.0).
//
// Perf forensics (all HBM-sourced weight-read rates, fills = 6.6-6.7 TB/s):
//   R6: GEMM cold 123 us = 2.2 TB/s; pipes idle (VALUBusy 5%, MfmaUtil 2.6%).
//   R7: k-phase de-lockstep       -> no change (temporal phase irrelevant).
//   R8: 4 KB contiguous runs      -> no change (run length 0.5-4 KB irrelevant).
//   R0: 64 KB linear region, per-lane nt loads, 4-ch blocks -> 435 us
//       (confounded regression; full linearity not the lever).
//   R1: NT aux bit on global_load_lds -> 368.0 us (no-op; cache policy dead).
//   Invariant across ALL variants: ~512 concurrent block-streams, and read
//   rate pinned at ~2.1 TB/s independent of per-stream pattern. Writes
//   (harness fill) hit 6.7 TB/s: MALL reorders/batches writes, but 512
//   interleaved read streams shred DRAM row locality (32 MB in flight /
//   2.2 TB/s = ~15 us queue latency -> queues full but row-thrashing).
//
// R2 (this): SINGLE VARIABLE = concurrent stream count. Double-buffered LDS
// (2 x 65792 B = 128.5 KB static) forces 1 block/CU -> 256 streams (was 512).
// Tile/pattern identical to R1. stage(t+1) issues right after the tile-t
// barrier so the stream stays continuous (1 barrier/tile instead of 2).

typedef __attribute__((ext_vector_type(4))) int    i32x4;
typedef __attribute__((ext_vector_type(4))) float  f32x4;
typedef __attribute__((ext_vector_type(8))) short  s16x8;
typedef __attribute__((ext_vector_type(8))) __bf16 bf16x8;

constexpr int K = 4096;
constexpr int N = 16384;
constexpr int BKI = 1024;                 // k-ints per tile (4 KB per row)
constexpr int NT = K / BKI;               // 4 tiles
constexpr int PITCH = 4096 + 16;          // LDS bytes per row (16B-aligned pad)
constexpr int BUFB = 16 * PITCH;          // 65792 B per buffer
constexpr size_t XB_OFF = 0;              // bf16 x: 32*4096*2 = 256 KB in d_ws

// fp32 -> bf16 RNE (finite inputs).
__device__ inline unsigned short f2bf_rne(float f) {
    unsigned u = __builtin_bit_cast(unsigned, f);
    u += 0x7FFF + ((u >> 16) & 1);
    return (unsigned short)(u >> 16);
}

// 8 int32 weights -> 8 bf16, exact (|w|<=127; fp32->bf16 truncation lossless).
__device__ inline bf16x8 cvtW(i32x4 lo, i32x4 hi) {
    s16x8 r;
#pragma unroll
    for (int i = 0; i < 4; ++i) {
        r[i]     = (short)(__builtin_bit_cast(unsigned, (float)lo[i]) >> 16);
        r[i + 4] = (short)(__builtin_bit_cast(unsigned, (float)hi[i]) >> 16);
    }
    return __builtin_bit_cast(bf16x8, r);
}

// ---- k1: x fp32 -> bf16 ----------------------------------------------------
__global__ __launch_bounds__(256) void xcvt_kernel(const float* __restrict__ x,
                                                   unsigned short* __restrict__ xb) {
    const int i = (blockIdx.x * 256 + threadIdx.x) * 8;
    f32x4 lo = *reinterpret_cast<const f32x4*>(x + i);
    f32x4 hi = *reinterpret_cast<const f32x4*>(x + i + 4);
    s16x8 r;
#pragma unroll
    for (int j = 0; j < 4; ++j) {
        r[j]     = (short)f2bf_rne(lo[j]);
        r[j + 4] = (short)f2bf_rne(hi[j]);
    }
    *reinterpret_cast<s16x8*>(xb + i) = r;
}

// ---- k2: GEMM, double-buffered LDS, 1 block/CU (256 streams) ---------------
__global__ __launch_bounds__(256, 1) void w8gemm_kernel(
    const __bf16* __restrict__ xb,
    const int* __restrict__ w,
    const float* __restrict__ scale,
    const float* __restrict__ bias,
    float* __restrict__ out)
{
    __shared__ char smem[2 * BUFB];   // 131584 B -> 1 block/CU

    const int tid  = threadIdx.x;
    const int lane = tid & 63;
    const int wave = tid >> 6;
    const int n16  = lane & 15;
    const int quad = lane >> 4;

    const int c0 = blockIdx.x * 16;       // 16 channels per block

    // Staging: wave w owns rows w*4..w*4+3; per tile, per row, 4 back-to-back
    // 1 KB global_load_lds into buffer it&1. aux=2 (NT) kept from R1 (neutral).
    auto stage = [&](int it) {
        char* buf = smem + (it & 1) * BUFB;
#pragma unroll
        for (int j = 0; j < 4; ++j) {
            const int row = wave * 4 + j;
            const char* gsrc = (const char*)(w + (size_t)(c0 + row) * K + it * BKI)
                               + (size_t)lane * 16;
            char* ldst = buf + row * PITCH + lane * 16;
#pragma unroll
            for (int s = 0; s < 4; ++s) {
                __builtin_amdgcn_global_load_lds(
                    (const __attribute__((address_space(1))) void*)(gsrc + s * 1024),
                    (__attribute__((address_space(3))) void*)(ldst + s * 1024),
                    16, 0, 2 /* NT */);
            }
        }
    };

    // Compute geometry: wave w consumes k-ints [w*256, w*256+256) of each tile.
    // B fragment (16x16x32): row n16, ints quad*8..+7 -> 2 x b128 from LDS.
    const int lro = n16 * PITCH + quad * 32 + wave * 1024;
    // A fragments from bf16 x (L2-hot): token n16 (acc0), n16+16 (acc1).
    const __bf16* __restrict__ xr0 = xb + (size_t)n16 * K + wave * 256 + quad * 8;
    const __bf16* __restrict__ xr1 = xr0 + (size_t)16 * K;

    f32x4 acc0 = {0.f, 0.f, 0.f, 0.f};
    f32x4 acc1 = {0.f, 0.f, 0.f, 0.f};

    stage(0);
#pragma unroll 1
    for (int it = 0; it < NT; ++it) {
        // Prefetch this tile's x fragments (8 k-steps x 2 halves x 16 B);
        // overlaps the stage(it) DMA drain.
        bf16x8 aX0[8], aX1[8];
#pragma unroll
        for (int j = 0; j < 8; ++j) {
            const int off = it * BKI + j * 32;
            aX0[j] = *reinterpret_cast<const bf16x8*>(xr0 + off);
            aX1[j] = *reinterpret_cast<const bf16x8*>(xr1 + off);
        }
        __syncthreads();   // compiler drains vmcnt(0): stage(it) visible; all
                           // waves done reading buffer (it+1)&1 (compute it-1)
        if (it + 1 < NT) stage(it + 1);   // into other buffer, overlaps compute
        const char* lrow = smem + (it & 1) * BUFB + lro;
#pragma unroll
        for (int j = 0; j < 8; ++j) {
            i32x4 b0 = *reinterpret_cast<const i32x4*>(lrow + j * 128);
            i32x4 b1 = *reinterpret_cast<const i32x4*>(lrow + j * 128 + 16);
            bf16x8 bf = cvtW(b0, b1);
            acc0 = __builtin_amdgcn_mfma_f32_16x16x32_bf16(aX0[j], bf, acc0, 0, 0, 0);
            acc1 = __builtin_amdgcn_mfma_f32_16x16x32_bf16(aX1[j], bf, acc1, 0, 0, 0);
        }
    }

    // Cross-wave reduction (4 k-quarter partials) + fused scale/bias epilogue.
    // Reduction area = first 8 KB of buffer 0; last compute read buffer 1.
    __syncthreads();
    float* red = (float*)smem;           // 4 waves x 512 floats = 8 KB
#pragma unroll
    for (int v = 0; v < 4; ++v) {
        red[wave * 512 + lane * 8 + v]     = acc0[v];
        red[wave * 512 + lane * 8 + 4 + v] = acc1[v];
    }
    __syncthreads();
#pragma unroll
    for (int pp = 0; pp < 2; ++pp) {
        const int p = tid + pp * 256;            // 0..511
        float s = red[p] + red[512 + p] + red[1024 + p] + red[1536 + p];
        const int pl   = p >> 3;                 // source lane
        const int r    = p & 7;
        const int half = r >> 2;                 // 0: tokens 0-15, 1: 16-31
        const int v    = r & 3;
        const int pn   = pl & 15;
        const int pq   = pl >> 4;
        const int token = half * 16 + pq * 4 + v;
        const int c = c0 + pn;
        out[(size_t)token * N + c] = s * scale[c] + bias[c];
    }
}

extern "C" void kernel_launch(void* const* d_in, const int* in_sizes, int n_in,
                              void* d_out, int out_size, void* d_ws, size_t ws_size,
                              hipStream_t stream) {
    const float* x     = (const float*)d_in[0];
    const int*   w     = (const int*)d_in[1];
    const float* scale = (const float*)d_in[2];
    const float* bias  = (const float*)d_in[3];
    float* out = (float*)d_out;

    unsigned short* xb = (unsigned short*)((char*)d_ws + XB_OFF);

    xcvt_kernel<<<dim3(64), dim3(256), 0, stream>>>(x, xb);
    w8gemm_kernel<<<dim3(N / 16), dim3(256), 0, stream>>>(
        (const __bf16*)xb, w, scale, bias, out);
}